// Round 8
// baseline (493.438 us; speedup 1.0000x reference)
//
#include <hip/hip_runtime.h>
#include <hip/hip_bf16.h>
#include <math.h>

constexpr int B_ = 4, L_ = 2048, IN_DIM = 3072, DM = 128, DI = 256, DS = 16, NL = 6;
constexpr int ROWS = B_ * L_; // 8192
constexpr int SPLITK = 8, KC = IN_DIM / SPLITK; // 384

static __device__ __forceinline__ float silu_f(float x) {
  return x / (1.f + __expf(-x));
}

// ---------------- split-K embedding GEMM (round-5 verified: 96 us) ----------------
// BM=64, BN=128 (full N), BK=32, 256 threads, 4x8 micro-tile, grid (8,128)=1024.
// No register prefetch: the SPLITK=12+prefetch variant tripled WRITE_SIZE
// (33->189 MB, scratch/partial traffic) and regressed 96->123 us.
__global__ __launch_bounds__(256) void gemm_emb_splitk(const float* __restrict__ A,
                                                       const float* __restrict__ Bv,
                                                       float* __restrict__ part) {
  constexpr int BM = 64, BK = 32;
  __shared__ float As[BK][BM + 4];
  __shared__ float Bs[BK][128 + 4];
  int split = blockIdx.x;          // 0..7
  int bm = blockIdx.y * BM;        // row block
  int kb = split * KC;
  int tid = threadIdx.x;
  int tm = tid >> 4, tn = tid & 15;
  float acc[4][8] = {};
  for (int k0 = 0; k0 < KC; k0 += BK) {
    // A tile 64x32: 512 float4, 2 per thread
#pragma unroll
    for (int p = 0; p < 2; ++p) {
      int i = tid + p * 256;
      int r = i >> 3, kq = (i & 7) * 4;
      float4 a4 = *(const float4*)&A[(size_t)(bm + r) * IN_DIM + kb + k0 + kq];
      As[kq + 0][r] = a4.x;
      As[kq + 1][r] = a4.y;
      As[kq + 2][r] = a4.z;
      As[kq + 3][r] = a4.w;
    }
    // B tile 32x128: 1024 float4, 4 per thread
#pragma unroll
    for (int p = 0; p < 4; ++p) {
      int i = tid + p * 256;
      int r = i >> 5, c = (i & 31) * 4;
      *(float4*)&Bs[r][c] = *(const float4*)&Bv[(size_t)(kb + k0 + r) * DM + c];
    }
    __syncthreads();
#pragma unroll
    for (int kk = 0; kk < BK; ++kk) {
      float4 a4 = *(const float4*)&As[kk][tm * 4];
      float4 b0 = *(const float4*)&Bs[kk][tn * 4];
      float4 b1 = *(const float4*)&Bs[kk][64 + tn * 4];
      float a[4] = {a4.x, a4.y, a4.z, a4.w};
      float b[8] = {b0.x, b0.y, b0.z, b0.w, b1.x, b1.y, b1.z, b1.w};
#pragma unroll
      for (int i = 0; i < 4; ++i)
#pragma unroll
        for (int j = 0; j < 8; ++j) acc[i][j] = fmaf(a[i], b[j], acc[i][j]);
    }
    __syncthreads();
  }
#pragma unroll
  for (int i = 0; i < 4; ++i) {
    size_t rowoff = ((size_t)split * ROWS + bm + tm * 4 + i) * DM;
    float4 o0 = {acc[i][0], acc[i][1], acc[i][2], acc[i][3]};
    float4 o1 = {acc[i][4], acc[i][5], acc[i][6], acc[i][7]};
    *(float4*)&part[rowoff + tn * 4] = o0;
    *(float4*)&part[rowoff + 64 + tn * 4] = o1;
  }
}

// ---------------- reduce split-K partials + bias -> h0 ; fused rmsnorm -> u ----------------
__global__ __launch_bounds__(256) void reduce_rms_kernel(const float* __restrict__ part,
                                                         const float* __restrict__ b_emb,
                                                         const float* __restrict__ norm_w,
                                                         float* __restrict__ h0,
                                                         float* __restrict__ u) {
  int wave = threadIdx.x >> 6, lane = threadIdx.x & 63;
  int row = blockIdx.x * 4 + wave;
  float sx = 0.f, sy = 0.f;
#pragma unroll
  for (int sp = 0; sp < SPLITK; ++sp) {
    float2 v = *(const float2*)(part + ((size_t)sp * ROWS + row) * DM + 2 * lane);
    sx += v.x;
    sy += v.y;
  }
  float2 be = *(const float2*)(b_emb + 2 * lane);
  sx += be.x;
  sy += be.y;
  float2 hv = {sx, sy};
  *(float2*)(h0 + (size_t)row * DM + 2 * lane) = hv;
  float ss = sx * sx + sy * sy;
#pragma unroll
  for (int o = 32; o >= 1; o >>= 1) ss += __shfl_xor(ss, o);
  float rs = 1.f / sqrtf(ss * (1.f / 128.f) + 1e-5f);
  float2 wv = *(const float2*)(norm_w + 2 * lane);
  float2 o2 = {sx * rs * wv.x, sy * rs * wv.y};
  *(float2*)(u + (size_t)row * DM + 2 * lane) = o2;
}

// ---------------- xz = u @ W_in : M=8192, K=128, N=512 ----------------
// BM=32, BN=128, BK=32, grid (4, 256) = 1024 blocks (4/CU), 2x8 micro-tile, prefetch.
__global__ __launch_bounds__(256) void gemm_in(const float* __restrict__ A,
                                               const float* __restrict__ Bv,
                                               float* __restrict__ C) {
  constexpr int BK = 32, N = 512;
  __shared__ float As[BK][32 + 4];
  __shared__ float Bs[BK][128 + 4];
  int bn = blockIdx.x * 128;
  int bm = blockIdx.y * 32;
  int tid = threadIdx.x;
  int tm = tid >> 4, tn = tid & 15;

  float4 pa, pb[4];
#define IN_PRELOAD(K0)                                                                   \
  {                                                                                      \
    int r = tid >> 3, kq = (tid & 7) * 4;                                                \
    pa = *(const float4*)&A[(size_t)(bm + r) * DM + (K0) + kq];                          \
    _Pragma("unroll") for (int p = 0; p < 4; ++p) {                                      \
      int i = tid + p * 256;                                                             \
      int rr = i >> 5, c = (i & 31) * 4;                                                 \
      pb[p] = *(const float4*)&Bv[(size_t)((K0) + rr) * N + bn + c];                     \
    }                                                                                    \
  }

  float acc[2][8] = {};
  IN_PRELOAD(0);
  for (int k0 = 0; k0 < DM; k0 += BK) {
    __syncthreads();
    {
      int r = tid >> 3, kq = (tid & 7) * 4;
      As[kq + 0][r] = pa.x;
      As[kq + 1][r] = pa.y;
      As[kq + 2][r] = pa.z;
      As[kq + 3][r] = pa.w;
    }
#pragma unroll
    for (int p = 0; p < 4; ++p) {
      int i = tid + p * 256;
      int rr = i >> 5, c = (i & 31) * 4;
      *(float4*)&Bs[rr][c] = pb[p];
    }
    __syncthreads();
    if (k0 + BK < DM) IN_PRELOAD(k0 + BK);
#pragma unroll
    for (int kk = 0; kk < BK; ++kk) {
      float2 a2 = *(const float2*)&As[kk][tm * 2];
      float4 b0 = *(const float4*)&Bs[kk][tn * 4];
      float4 b1 = *(const float4*)&Bs[kk][64 + tn * 4];
      float b[8] = {b0.x, b0.y, b0.z, b0.w, b1.x, b1.y, b1.z, b1.w};
#pragma unroll
      for (int j = 0; j < 8; ++j) acc[0][j] = fmaf(a2.x, b[j], acc[0][j]);
#pragma unroll
      for (int j = 0; j < 8; ++j) acc[1][j] = fmaf(a2.y, b[j], acc[1][j]);
    }
  }
#undef IN_PRELOAD
#pragma unroll
  for (int i = 0; i < 2; ++i) {
    size_t rowoff = (size_t)(bm + tm * 2 + i) * N + bn;
    float4 o0 = {acc[i][0], acc[i][1], acc[i][2], acc[i][3]};
    float4 o1 = {acc[i][4], acc[i][5], acc[i][6], acc[i][7]};
    *(float4*)&C[rowoff + tn * 4] = o0;
    *(float4*)&C[rowoff + 64 + tn * 4] = o1;
  }
}

// ---------------- causal depthwise conv (k=4) + bias + silu ----------------
__global__ __launch_bounds__(256) void conv_silu_kernel(const float* __restrict__ xz,
                                                        const float* __restrict__ conv_w,
                                                        const float* __restrict__ conv_b,
                                                        float* __restrict__ xs_row,
                                                        float* __restrict__ xs_T) {
  __shared__ float tile[64][65];
  __shared__ float cw[64][4];
  __shared__ float cb[64];
  int b = blockIdx.z, l0 = blockIdx.y * 64, c0 = blockIdx.x * 64;
  int tid = threadIdx.x;
  cw[tid / 4][tid % 4] = conv_w[(size_t)c0 * 4 + tid];
  if (tid < 64) cb[tid] = conv_b[c0 + tid];
  __syncthreads();
  int cl = tid % 64;
  int lbase = tid / 64;  // 0..3
#pragma unroll
  for (int i = 0; i < 16; ++i) {
    int ll = lbase + 4 * i;
    int l = l0 + ll;
    float acc = cb[cl];
#pragma unroll
    for (int k = 0; k < 4; ++k) {
      int li = l + k - 3;
      if (li >= 0) acc = fmaf(xz[((size_t)(b * L_ + li)) * 512 + c0 + cl], cw[cl][k], acc);
    }
    tile[ll][cl] = silu_f(acc);
  }
  __syncthreads();
  for (int i = tid; i < 4096; i += 256) {
    int lr = i / 64, c = i % 64;
    xs_row[((size_t)(b * L_ + l0 + lr)) * DI + c0 + c] = tile[lr][c];
  }
  for (int i = tid; i < 4096; i += 256) {
    int c = i / 64, lr = i % 64;
    xs_T[((size_t)(b * DI + c0 + c)) * L_ + l0 + lr] = tile[lr][c];
  }
}

// ---------------- dbl = xs @ W_x (256 -> 40) ----------------
// 8 rows/block, grid 1024 (4 blocks/CU). No W_x LDS stage: direct global reads
// (40 KB table, L1-broadcast across the 8 threads sharing a row) keeps LDS at
// 8 KB so occupancy isn't LDS-capped. thread: r=tid>>5 (row), q=tid&31 (col),
// cols q and 32+q (latter only for q<8).
__global__ __launch_bounds__(256) void dbl_kernel(const float* __restrict__ xs_row,
                                                  const float* __restrict__ W_x,
                                                  float* __restrict__ dbl) {
  __shared__ float Xs[8][260];
  int tid = threadIdx.x;
  int r0 = blockIdx.x * 8;
  for (int i = tid; i < 8 * 64; i += 256) {
    int r = i >> 6, kq = (i & 63) * 4;
    float4 v = *(const float4*)&xs_row[(size_t)(r0 + r) * DI + kq];
    Xs[r][kq + 0] = v.x;
    Xs[r][kq + 1] = v.y;
    Xs[r][kq + 2] = v.z;
    Xs[r][kq + 3] = v.w;
  }
  __syncthreads();
  int r = tid >> 5, q = tid & 31;
  float acc0 = 0.f, acc1 = 0.f;
  for (int k = 0; k < 256; ++k) {
    float v = Xs[r][k];
    acc0 = fmaf(v, W_x[k * 40 + q], acc0);
    if (q < 8) acc1 = fmaf(v, W_x[k * 40 + 32 + q], acc1);
  }
  dbl[(size_t)(r0 + r) * 40 + q] = acc0;
  if (q < 8) dbl[(size_t)(r0 + r) * 40 + 32 + q] = acc1;
}

// ---------------- delta = softplus(dt @ W_dt + b_dt), transposed ----------------
// 8 rows/block, grid 1024 (4 blocks/CU); LDS = Dt 0.25K + Wdt 8K + Tile 8K.
__global__ __launch_bounds__(256) void delta_kernel(const float* __restrict__ dbl,
                                                    const float* __restrict__ W_dt,
                                                    const float* __restrict__ b_dt,
                                                    float* __restrict__ delta_T) {
  __shared__ float Dt[8][8];
  __shared__ float Wdt[8 * 256];
  __shared__ float Tile[8][257];
  int tid = threadIdx.x;
  int r0 = blockIdx.x * 8;
  int b = r0 / L_, l0 = r0 % L_;
  if (tid < 64) {
    int r = tid >> 3, k = tid & 7;
    Dt[r][k] = dbl[(size_t)(r0 + r) * 40 + k];
  }
  for (int i = tid; i < 8 * 256; i += 256) Wdt[i] = W_dt[i];
  __syncthreads();
  int c = tid;
  float bd = b_dt[c];
#pragma unroll
  for (int r = 0; r < 8; ++r) {
    float a = bd;
#pragma unroll
    for (int k = 0; k < 8; ++k) a = fmaf(Dt[r][k], Wdt[k * 256 + c], a);
    Tile[r][c] = (a > 20.f) ? a : log1pf(__expf(a));
  }
  __syncthreads();
  for (int i = tid; i < 8 * 256; i += 256) {
    int cc = i >> 3, rr = i & 7;
    delta_T[((size_t)(b * DI + cc)) * L_ + l0 + rr] = Tile[rr][cc];
  }
}

// ---------------- chunked parallel selective scan + fused ypost ----------------
__global__ __launch_bounds__(512) void scan_kernel(const float* __restrict__ delta_T,
                                                   const float* __restrict__ xs_T,
                                                   const float* __restrict__ dbl,
                                                   const float* __restrict__ A_log,
                                                   const float* __restrict__ Dp,
                                                   const float* __restrict__ xz,
                                                   float* __restrict__ y) {
  __shared__ float s_aprod[32][16];
  __shared__ float s_hend[32][16];
  __shared__ float s_hstart[32][16];
  int tid = threadIdx.x;
  int k = tid >> 4, s = tid & 15;   // chunk, state
  int g = blockIdx.x;               // b*256 + c
  int b = g >> 8, c = g & 255;
  float A = -__expf(A_log[c * DS + s]);
  float dpc = Dp[c];
  const float* dp = delta_T + (size_t)g * L_ + k * 64;
  const float* xp = xs_T + (size_t)g * L_ + k * 64;
  const float* bp = dbl + ((size_t)(b * L_ + k * 64)) * 40 + 8 + s;
  const float* cp = dbl + ((size_t)(b * L_ + k * 64)) * 40 + 24 + s;

  float aprod = 1.f, h = 0.f;
  for (int j = 0; j < 64; j += 4) {
    float4 d4 = *(const float4*)(dp + j);
    float4 x4 = *(const float4*)(xp + j);
    float dj[4] = {d4.x, d4.y, d4.z, d4.w};
    float xj[4] = {x4.x, x4.y, x4.z, x4.w};
#pragma unroll
    for (int u = 0; u < 4; ++u) {
      float Bv = bp[(size_t)(j + u) * 40];
      float dA = __expf(dj[u] * A);
      aprod *= dA;
      h = fmaf(dA, h, dj[u] * Bv * xj[u]);
    }
  }
  s_aprod[k][s] = aprod;
  s_hend[k][s] = h;
  __syncthreads();

  if (tid < 16) {
    float hh = 0.f;
    for (int kk = 0; kk < 32; ++kk) {
      s_hstart[kk][tid] = hh;
      hh = fmaf(s_aprod[kk][tid], hh, s_hend[kk][tid]);
    }
  }
  __syncthreads();

  h = s_hstart[k][s];
  float* yp = y + ((size_t)(b * L_) + k * 64) * DI + c;
  const float* rp = xz + ((size_t)(b * L_) + k * 64) * 512 + 256 + c;
  for (int j = 0; j < 64; j += 4) {
    float4 d4 = *(const float4*)(dp + j);
    float4 x4 = *(const float4*)(xp + j);
    float dj[4] = {d4.x, d4.y, d4.z, d4.w};
    float xj[4] = {x4.x, x4.y, x4.z, x4.w};
#pragma unroll
    for (int u = 0; u < 4; ++u) {
      float Bv = bp[(size_t)(j + u) * 40];
      float Cv = cp[(size_t)(j + u) * 40];
      float dA = __expf(dj[u] * A);
      h = fmaf(dA, h, dj[u] * Bv * xj[u]);
      float p = h * Cv;
      p += __shfl_xor(p, 8, 16);
      p += __shfl_xor(p, 4, 16);
      p += __shfl_xor(p, 2, 16);
      p += __shfl_xor(p, 1, 16);
      if (s == 0) {
        float res = rp[(size_t)(j + u) * 512];
        yp[(size_t)(j + u) * DI] = (p + xj[u] * dpc) * silu_f(res);
      }
    }
  }
}

// ---------------- final fused: ob = y@W_out; +h0; rmsnorm; head; softmax; argmax ----------------
// BM=16, BN=128 (full), BK=32, grid 512 (2/CU), prefetch. Epilogue via 16-lane shuffles.
__global__ __launch_bounds__(256) void final_gemm_kernel(const float* __restrict__ y,
                                                         const float* __restrict__ W_out,
                                                         const float* __restrict__ h0,
                                                         const float* __restrict__ normf_w,
                                                         const float* __restrict__ W_head,
                                                         const float* __restrict__ b_head,
                                                         float* __restrict__ pi_out,
                                                         float* __restrict__ pred_out) {
  constexpr int BK = 32;
  __shared__ float As[BK][16 + 4];
  __shared__ float Bs[BK][128 + 4];
  __shared__ float Wh[128 * 6];
  int tid = threadIdx.x;
  int tm = tid >> 4, tn = tid & 15;
  int bm = blockIdx.x * 16;
  for (int i = tid; i < 768; i += 256) Wh[i] = W_head[i];

  float4 pa, pb[4];
#define FN_PRELOAD(K0)                                                                   \
  {                                                                                      \
    if (tid < 128) {                                                                     \
      int r = tid >> 3, kq = (tid & 7) * 4;                                              \
      pa = *(const float4*)&y[(size_t)(bm + r) * DI + (K0) + kq];                        \
    }                                                                                    \
    _Pragma("unroll") for (int p = 0; p < 4; ++p) {                                      \
      int i = tid + p * 256;                                                             \
      int rr = i >> 5, c = (i & 31) * 4;                                                 \
      pb[p] = *(const float4*)&W_out[(size_t)((K0) + rr) * DM + c];                      \
    }                                                                                    \
  }

  float acc[8] = {};
  FN_PRELOAD(0);
  for (int k0 = 0; k0 < DI; k0 += BK) {
    __syncthreads();
    if (tid < 128) {
      int r = tid >> 3, kq = (tid & 7) * 4;
      As[kq + 0][r] = pa.x;
      As[kq + 1][r] = pa.y;
      As[kq + 2][r] = pa.z;
      As[kq + 3][r] = pa.w;
    }
#pragma unroll
    for (int p = 0; p < 4; ++p) {
      int i = tid + p * 256;
      int rr = i >> 5, c = (i & 31) * 4;
      *(float4*)&Bs[rr][c] = pb[p];
    }
    __syncthreads();
    if (k0 + BK < DI) FN_PRELOAD(k0 + BK);
#pragma unroll
    for (int kk = 0; kk < BK; ++kk) {
      float a0 = As[kk][tm];
      float4 b0 = *(const float4*)&Bs[kk][tn * 4];
      float4 b1 = *(const float4*)&Bs[kk][64 + tn * 4];
      float b[8] = {b0.x, b0.y, b0.z, b0.w, b1.x, b1.y, b1.z, b1.w};
#pragma unroll
      for (int j = 0; j < 8; ++j) acc[j] = fmaf(a0, b[j], acc[j]);
    }
  }
#undef FN_PRELOAD
  // epilogue: this thread owns row bm+tm, cols tn*4..+3 and 64+tn*4..+3
  float4 nwa = *(const float4*)&normf_w[tn * 4];
  float4 nwb = *(const float4*)&normf_w[64 + tn * 4];
  float nw[8] = {nwa.x, nwa.y, nwa.z, nwa.w, nwb.x, nwb.y, nwb.z, nwb.w};
  float bh[6];
#pragma unroll
  for (int j = 0; j < 6; ++j) bh[j] = b_head[j];
  int row = bm + tm;
  float4 h0a = *(const float4*)&h0[(size_t)row * DM + tn * 4];
  float4 h0b = *(const float4*)&h0[(size_t)row * DM + 64 + tn * 4];
  float hv[8] = {acc[0] + h0a.x, acc[1] + h0a.y, acc[2] + h0a.z, acc[3] + h0a.w,
                 acc[4] + h0b.x, acc[5] + h0b.y, acc[6] + h0b.z, acc[7] + h0b.w};
  float ss = 0.f;
#pragma unroll
  for (int j = 0; j < 8; ++j) ss += hv[j] * hv[j];
  ss += __shfl_xor(ss, 1);
  ss += __shfl_xor(ss, 2);
  ss += __shfl_xor(ss, 4);
  ss += __shfl_xor(ss, 8);
  float rs = 1.f / sqrtf(ss * (1.f / 128.f) + 1e-5f);
  float lg[6] = {};
#pragma unroll
  for (int j = 0; j < 8; ++j) {
    float fm = hv[j] * rs * nw[j];
    int col = (j < 4) ? (tn * 4 + j) : (64 + tn * 4 + (j - 4));
#pragma unroll
    for (int l = 0; l < 6; ++l) lg[l] = fmaf(fm, Wh[col * 6 + l], lg[l]);
  }
#pragma unroll
  for (int l = 0; l < 6; ++l) {
    lg[l] += __shfl_xor(lg[l], 1);
    lg[l] += __shfl_xor(lg[l], 2);
    lg[l] += __shfl_xor(lg[l], 4);
    lg[l] += __shfl_xor(lg[l], 8);
    lg[l] += bh[l];
  }
  if (tn == 0) {
    float mv = lg[0];
    int am = 0;
#pragma unroll
    for (int l = 1; l < 6; ++l)
      if (lg[l] > mv) { mv = lg[l]; am = l; }
    float e[6], sum = 0.f;
#pragma unroll
    for (int l = 0; l < 6; ++l) { e[l] = __expf(lg[l] - mv); sum += e[l]; }
    float inv = 1.f / sum;
#pragma unroll
    for (int l = 0; l < 6; ++l) pi_out[(size_t)row * NL + l] = e[l] * inv;
    pred_out[row] = (float)am;
  }
}

extern "C" void kernel_launch(void* const* d_in, const int* in_sizes, int n_in,
                              void* d_out, int out_size, void* d_ws, size_t ws_size,
                              hipStream_t stream) {
  const float* x = (const float*)d_in[0];
  const float* W_emb = (const float*)d_in[1];
  const float* b_emb = (const float*)d_in[2];
  const float* norm_w = (const float*)d_in[3];
  const float* W_in = (const float*)d_in[4];
  const float* conv_w = (const float*)d_in[5];
  const float* conv_b = (const float*)d_in[6];
  const float* W_x = (const float*)d_in[7];
  const float* W_dt = (const float*)d_in[8];
  const float* b_dt = (const float*)d_in[9];
  const float* A_log = (const float*)d_in[10];
  const float* Dp = (const float*)d_in[11];
  const float* W_out = (const float*)d_in[12];
  const float* normf_w = (const float*)d_in[13];
  const float* W_head = (const float*)d_in[14];
  const float* b_head = (const float*)d_in[15];

  float* ws = (float*)d_ws;
  float* h0 = ws;                      // 8192*128
  float* u = h0 + 1048576;             // 8192*128
  float* xz = u + 1048576;             // 8192*512
  float* xs_row = xz + 4194304;        // 8192*256
  float* xs_T = xs_row + 2097152;      // 1024*2048
  float* dbl = xs_T + 2097152;         // 8192*40
  float* delta_T = dbl + 327680;       // 1024*2048
  float* y = delta_T + 2097152;        // 8192*256

  // split-K partials (8*8192*128 = 8,388,608 floats) alias xz+xs_row+xs_T
  // (exactly 4,194,304+2,097,152+2,097,152) — dead before xz is written.
  float* part = xz;

  float* pi_out = (float*)d_out;
  float* pred_out = pi_out + (size_t)ROWS * NL;

  // 1) split-K emb GEMM -> partials
  gemm_emb_splitk<<<dim3(SPLITK, ROWS / 64), 256, 0, stream>>>(x, W_emb, part);
  // 2) reduce partials + bias -> h0; fused rmsnorm -> u
  reduce_rms_kernel<<<ROWS / 4, 256, 0, stream>>>(part, b_emb, norm_w, h0, u);
  // 3) xz = u @ W_in
  gemm_in<<<dim3(4, 256), 256, 0, stream>>>(u, W_in, xz);
  // 4) xs = silu(causal_dwconv(xz[:, :256]))
  conv_silu_kernel<<<dim3(4, 32, 4), 256, 0, stream>>>(xz, conv_w, conv_b, xs_row, xs_T);
  // 5) dbl = xs @ W_x  (8 rows/block, 4 blocks/CU)
  dbl_kernel<<<1024, 256, 0, stream>>>(xs_row, W_x, dbl);
  // 6) delta = softplus(dt @ W_dt + b_dt)  (transposed store, 8 rows/block)
  delta_kernel<<<1024, 256, 0, stream>>>(dbl, W_dt, b_dt, delta_T);
  // 7) chunked parallel selective scan + fused ypost
  scan_kernel<<<1024, 512, 0, stream>>>(delta_T, xs_T, dbl, A_log, Dp, xz, y);
  // 8) final fused GEMM + residual + rmsnorm + head + softmax + argmax
  final_gemm_kernel<<<512, 256, 0, stream>>>(y, W_out, h0, normf_w, W_head, b_head, pi_out, pred_out);
}

// Round 9
// 377.458 us; speedup vs baseline: 1.3073x; 1.3073x over previous
//
#include <hip/hip_runtime.h>
#include <hip/hip_bf16.h>
#include <math.h>

constexpr int B_ = 4, L_ = 2048, IN_DIM = 3072, DM = 128, DI = 256, DS = 16, NL = 6;
constexpr int ROWS = B_ * L_; // 8192
constexpr int SPLITK = 8, KC = IN_DIM / SPLITK; // 384

typedef __attribute__((ext_vector_type(8))) short short8b;  // 8 bf16 (4 VGPRs)
typedef __attribute__((ext_vector_type(4))) float f32x4;

static __device__ __forceinline__ float silu_f(float x) {
  return x / (1.f + __expf(-x));
}

static __device__ __forceinline__ unsigned short f2bf_rne(float v) {
  unsigned u = __float_as_uint(v);
  unsigned r = u + 0x7FFFu + ((u >> 16) & 1u);
  return (unsigned short)(r >> 16);
}

// ---------------- prep: W_emb (3072x128 f32) -> transposed bf16 hi/lo [c][k] ----------------
__global__ __launch_bounds__(256) void wsplit_kernel(const float* __restrict__ W,
                                                     unsigned short* __restrict__ wt_hi,
                                                     unsigned short* __restrict__ wt_lo) {
  int tid = threadIdx.x;
  int c = tid & 127;
  int kc = blockIdx.x * 16 + (tid >> 7) * 8;
  short8b vh, vl;
#pragma unroll
  for (int j = 0; j < 8; ++j) {
    float v = W[(size_t)(kc + j) * DM + c];
    unsigned short h = f2bf_rne(v);
    float hf = __uint_as_float((unsigned)h << 16);
    vh[j] = (short)h;
    vl[j] = (short)f2bf_rne(v - hf);
  }
  *(short8b*)&wt_hi[(size_t)c * IN_DIM + kc] = vh;
  *(short8b*)&wt_lo[(size_t)c * IN_DIM + kc] = vl;
}

// ---------------- split-K embedding GEMM via bf16 hi/lo MFMA ----------------
// BM=64, BN=128(full), BK=32, 4 waves; wave w owns rows 16w..16w+15, all 8 col-tiles.
// Per k-step: 3 mfma_f32_16x16x32_bf16 per col-tile (hi*hi + hi*lo + lo*hi).
// Error ~1e-5 on h0 (products exact in f32 accum; dropped lo*lo ~2^-18).
__global__ __launch_bounds__(256) void gemm_emb_mfma(const float* __restrict__ A,
                                                     const unsigned short* __restrict__ wt_hi,
                                                     const unsigned short* __restrict__ wt_lo,
                                                     float* __restrict__ part) {
  constexpr int BM = 64, BK = 32, LDA = 40;  // +8 bf16 pad: row stride 80B spreads banks
  __shared__ unsigned short Ah[BM][LDA], Al[BM][LDA];
  __shared__ unsigned short Bh[DM][LDA], Bl[DM][LDA];
  int split = blockIdx.x;
  int bm = blockIdx.y * BM;
  int kb = split * KC;
  int tid = threadIdx.x;
  int w = tid >> 6, l = tid & 63;
  int fr = l & 15, fk = (l >> 4) * 8;

  f32x4 acc[8] = {};

  for (int k0 = 0; k0 < KC; k0 += BK) {
    // stage A: x tile 64x32 f32 -> bf16 hi/lo (each thread 8 elems)
    {
      int r = tid >> 2, kq = (tid & 3) * 8;
      const float* src = &A[(size_t)(bm + r) * IN_DIM + kb + k0 + kq];
      float4 v0 = *(const float4*)src;
      float4 v1 = *(const float4*)(src + 4);
      float vv[8] = {v0.x, v0.y, v0.z, v0.w, v1.x, v1.y, v1.z, v1.w};
      short8b vh, vl;
#pragma unroll
      for (int j = 0; j < 8; ++j) {
        unsigned short h = f2bf_rne(vv[j]);
        float hf = __uint_as_float((unsigned)h << 16);
        vh[j] = (short)h;
        vl[j] = (short)f2bf_rne(vv[j] - hf);
      }
      *(short8b*)&Ah[r][kq] = vh;
      *(short8b*)&Al[r][kq] = vl;
    }
    // stage B: pre-split Wt bf16 [c][k] -> LDS (each thread 16 bf16 hi + 16 lo)
    {
      int c = tid >> 1, kq = (tid & 1) * 16;
      const unsigned short* sh = &wt_hi[(size_t)c * IN_DIM + kb + k0 + kq];
      const unsigned short* sl = &wt_lo[(size_t)c * IN_DIM + kb + k0 + kq];
      *(short8b*)&Bh[c][kq] = *(const short8b*)sh;
      *(short8b*)&Bh[c][kq + 8] = *(const short8b*)(sh + 8);
      *(short8b*)&Bl[c][kq] = *(const short8b*)sl;
      *(short8b*)&Bl[c][kq + 8] = *(const short8b*)(sl + 8);
    }
    __syncthreads();
    short8b ah = *(short8b*)&Ah[16 * w + fr][fk];
    short8b al = *(short8b*)&Al[16 * w + fr][fk];
#pragma unroll
    for (int t = 0; t < 8; ++t) {
      short8b bh = *(short8b*)&Bh[16 * t + fr][fk];
      short8b bl = *(short8b*)&Bl[16 * t + fr][fk];
      acc[t] = __builtin_amdgcn_mfma_f32_16x16x32_bf16(ah, bh, acc[t], 0, 0, 0);
      acc[t] = __builtin_amdgcn_mfma_f32_16x16x32_bf16(ah, bl, acc[t], 0, 0, 0);
      acc[t] = __builtin_amdgcn_mfma_f32_16x16x32_bf16(al, bh, acc[t], 0, 0, 0);
    }
    __syncthreads();
  }
  // epilogue: C/D layout col=lane&15, row=(lane>>4)*4+reg (m89-verified)
  int orow = bm + 16 * w + (l >> 4) * 4;
#pragma unroll
  for (int t = 0; t < 8; ++t) {
#pragma unroll
    for (int r = 0; r < 4; ++r) {
      part[((size_t)split * ROWS + orow + r) * DM + 16 * t + fr] = acc[t][r];
    }
  }
}

// ---------------- reduce split-K partials + bias -> h0 ; fused rmsnorm -> u ----------------
__global__ __launch_bounds__(256) void reduce_rms_kernel(const float* __restrict__ part,
                                                         const float* __restrict__ b_emb,
                                                         const float* __restrict__ norm_w,
                                                         float* __restrict__ h0,
                                                         float* __restrict__ u) {
  int wave = threadIdx.x >> 6, lane = threadIdx.x & 63;
  int row = blockIdx.x * 4 + wave;
  float sx = 0.f, sy = 0.f;
#pragma unroll
  for (int sp = 0; sp < SPLITK; ++sp) {
    float2 v = *(const float2*)(part + ((size_t)sp * ROWS + row) * DM + 2 * lane);
    sx += v.x;
    sy += v.y;
  }
  float2 be = *(const float2*)(b_emb + 2 * lane);
  sx += be.x;
  sy += be.y;
  float2 hv = {sx, sy};
  *(float2*)(h0 + (size_t)row * DM + 2 * lane) = hv;
  float ss = sx * sx + sy * sy;
#pragma unroll
  for (int o = 32; o >= 1; o >>= 1) ss += __shfl_xor(ss, o);
  float rs = 1.f / sqrtf(ss * (1.f / 128.f) + 1e-5f);
  float2 wv = *(const float2*)(norm_w + 2 * lane);
  float2 o2 = {sx * rs * wv.x, sy * rs * wv.y};
  *(float2*)(u + (size_t)row * DM + 2 * lane) = o2;
}

// ---------------- xz = u @ W_in : M=8192, K=128, N=512 (round-5 verified) ----------------
__global__ __launch_bounds__(256) void gemm_in(const float* __restrict__ A,
                                               const float* __restrict__ Bv,
                                               float* __restrict__ C) {
  constexpr int BM = 64, BK = 32, N = 512;
  __shared__ float As[BK][BM + 4];
  __shared__ float Bs[BK][128 + 4];
  int bn = blockIdx.x * 128;
  int bm = blockIdx.y * BM;
  int tid = threadIdx.x;
  int tm = tid >> 4, tn = tid & 15;
  float acc[4][8] = {};
  for (int k0 = 0; k0 < DM; k0 += BK) {
#pragma unroll
    for (int p = 0; p < 2; ++p) {
      int i = tid + p * 256;
      int r = i >> 3, kq = (i & 7) * 4;
      float4 a4 = *(const float4*)&A[(size_t)(bm + r) * DM + k0 + kq];
      As[kq + 0][r] = a4.x;
      As[kq + 1][r] = a4.y;
      As[kq + 2][r] = a4.z;
      As[kq + 3][r] = a4.w;
    }
#pragma unroll
    for (int p = 0; p < 4; ++p) {
      int i = tid + p * 256;
      int r = i >> 5, c = (i & 31) * 4;
      *(float4*)&Bs[r][c] = *(const float4*)&Bv[(size_t)(k0 + r) * N + bn + c];
    }
    __syncthreads();
#pragma unroll
    for (int kk = 0; kk < BK; ++kk) {
      float4 a4 = *(const float4*)&As[kk][tm * 4];
      float4 b0 = *(const float4*)&Bs[kk][tn * 4];
      float4 b1 = *(const float4*)&Bs[kk][64 + tn * 4];
      float a[4] = {a4.x, a4.y, a4.z, a4.w};
      float b[8] = {b0.x, b0.y, b0.z, b0.w, b1.x, b1.y, b1.z, b1.w};
#pragma unroll
      for (int i = 0; i < 4; ++i)
#pragma unroll
        for (int j = 0; j < 8; ++j) acc[i][j] = fmaf(a[i], b[j], acc[i][j]);
    }
    __syncthreads();
  }
#pragma unroll
  for (int i = 0; i < 4; ++i) {
    size_t rowoff = (size_t)(bm + tm * 4 + i) * N + bn;
    float4 o0 = {acc[i][0], acc[i][1], acc[i][2], acc[i][3]};
    float4 o1 = {acc[i][4], acc[i][5], acc[i][6], acc[i][7]};
    *(float4*)&C[rowoff + tn * 4] = o0;
    *(float4*)&C[rowoff + 64 + tn * 4] = o1;
  }
}

// ---------------- causal depthwise conv (k=4) + bias + silu ----------------
__global__ __launch_bounds__(256) void conv_silu_kernel(const float* __restrict__ xz,
                                                        const float* __restrict__ conv_w,
                                                        const float* __restrict__ conv_b,
                                                        float* __restrict__ xs_row,
                                                        float* __restrict__ xs_T) {
  __shared__ float tile[64][65];
  __shared__ float cw[64][4];
  __shared__ float cb[64];
  int b = blockIdx.z, l0 = blockIdx.y * 64, c0 = blockIdx.x * 64;
  int tid = threadIdx.x;
  cw[tid / 4][tid % 4] = conv_w[(size_t)c0 * 4 + tid];
  if (tid < 64) cb[tid] = conv_b[c0 + tid];
  __syncthreads();
  int cl = tid % 64;
  int lbase = tid / 64;  // 0..3
#pragma unroll
  for (int i = 0; i < 16; ++i) {
    int ll = lbase + 4 * i;
    int l = l0 + ll;
    float acc = cb[cl];
#pragma unroll
    for (int k = 0; k < 4; ++k) {
      int li = l + k - 3;
      if (li >= 0) acc = fmaf(xz[((size_t)(b * L_ + li)) * 512 + c0 + cl], cw[cl][k], acc);
    }
    tile[ll][cl] = silu_f(acc);
  }
  __syncthreads();
  for (int i = tid; i < 4096; i += 256) {
    int lr = i / 64, c = i % 64;
    xs_row[((size_t)(b * L_ + l0 + lr)) * DI + c0 + c] = tile[lr][c];
  }
  for (int i = tid; i < 4096; i += 256) {
    int c = i / 64, lr = i % 64;
    xs_T[((size_t)(b * DI + c0 + c)) * L_ + l0 + lr] = tile[lr][c];
  }
}

// ---------------- dbl = xs @ W_x (256 -> 40), 32 rows/block, grid 256 (round-5) ----------------
__global__ __launch_bounds__(256) void dbl_kernel(const float* __restrict__ xs_row,
                                                  const float* __restrict__ W_x,
                                                  float* __restrict__ dbl) {
  __shared__ float Xs[32][257];
  __shared__ float Wx[256 * 40];
  int tid = threadIdx.x;
  int r0 = blockIdx.x * 32;
  for (int i = tid; i < 32 * 64; i += 256) {
    int r = i >> 6, kq = (i & 63) * 4;
    float4 v = *(const float4*)&xs_row[(size_t)(r0 + r) * DI + kq];
    Xs[r][kq + 0] = v.x;
    Xs[r][kq + 1] = v.y;
    Xs[r][kq + 2] = v.z;
    Xs[r][kq + 3] = v.w;
  }
  for (int i = tid; i < 256 * 40; i += 256) Wx[i] = W_x[i];
  __syncthreads();
  int r = tid & 31, q = tid >> 5;  // q in 0..7 -> output cols q*5..q*5+4
  float acc[5] = {};
  for (int k = 0; k < 256; ++k) {
    float v = Xs[r][k];
#pragma unroll
    for (int j = 0; j < 5; ++j) acc[j] = fmaf(v, Wx[k * 40 + q * 5 + j], acc[j]);
  }
#pragma unroll
  for (int j = 0; j < 5; ++j) dbl[(size_t)(r0 + r) * 40 + q * 5 + j] = acc[j];
}

// ---------------- delta = softplus(dt @ W_dt + b_dt), transposed, 32 rows/block (round-5) ----
__global__ __launch_bounds__(256) void delta_kernel(const float* __restrict__ dbl,
                                                    const float* __restrict__ W_dt,
                                                    const float* __restrict__ b_dt,
                                                    float* __restrict__ delta_T) {
  __shared__ float Tile[32][257];
  __shared__ float Dt[32][8];
  __shared__ float Wdt[8 * 256];
  int tid = threadIdx.x;
  int r0 = blockIdx.x * 32;
  int b = r0 / L_, l0 = r0 % L_;
  if (tid < 256) {
    int r = tid >> 3, k = tid & 7;
    Dt[r][k] = dbl[(size_t)(r0 + r) * 40 + k];
  }
  for (int i = tid; i < 8 * 256; i += 256) Wdt[i] = W_dt[i];
  __syncthreads();
  int c = tid;
  float bd = b_dt[c];
  for (int r = 0; r < 32; ++r) {
    float a = bd;
#pragma unroll
    for (int k = 0; k < 8; ++k) a = fmaf(Dt[r][k], Wdt[k * 256 + c], a);
    Tile[r][c] = (a > 20.f) ? a : log1pf(__expf(a));
  }
  __syncthreads();
  for (int i = tid; i < 32 * 256; i += 256) {
    int cc = i >> 5, rr = i & 31;
    delta_T[((size_t)(b * DI + cc)) * L_ + l0 + rr] = Tile[rr][cc];
  }
}

// ---------------- chunked parallel selective scan + fused ypost ----------------
__global__ __launch_bounds__(512) void scan_kernel(const float* __restrict__ delta_T,
                                                   const float* __restrict__ xs_T,
                                                   const float* __restrict__ dbl,
                                                   const float* __restrict__ A_log,
                                                   const float* __restrict__ Dp,
                                                   const float* __restrict__ xz,
                                                   float* __restrict__ y) {
  __shared__ float s_aprod[32][16];
  __shared__ float s_hend[32][16];
  __shared__ float s_hstart[32][16];
  int tid = threadIdx.x;
  int k = tid >> 4, s = tid & 15;   // chunk, state
  int g = blockIdx.x;               // b*256 + c
  int b = g >> 8, c = g & 255;
  float A = -__expf(A_log[c * DS + s]);
  float dpc = Dp[c];
  const float* dp = delta_T + (size_t)g * L_ + k * 64;
  const float* xp = xs_T + (size_t)g * L_ + k * 64;
  const float* bp = dbl + ((size_t)(b * L_ + k * 64)) * 40 + 8 + s;
  const float* cp = dbl + ((size_t)(b * L_ + k * 64)) * 40 + 24 + s;

  float aprod = 1.f, h = 0.f;
  for (int j = 0; j < 64; j += 4) {
    float4 d4 = *(const float4*)(dp + j);
    float4 x4 = *(const float4*)(xp + j);
    float dj[4] = {d4.x, d4.y, d4.z, d4.w};
    float xj[4] = {x4.x, x4.y, x4.z, x4.w};
#pragma unroll
    for (int u = 0; u < 4; ++u) {
      float Bv = bp[(size_t)(j + u) * 40];
      float dA = __expf(dj[u] * A);
      aprod *= dA;
      h = fmaf(dA, h, dj[u] * Bv * xj[u]);
    }
  }
  s_aprod[k][s] = aprod;
  s_hend[k][s] = h;
  __syncthreads();

  if (tid < 16) {
    float hh = 0.f;
    for (int kk = 0; kk < 32; ++kk) {
      s_hstart[kk][tid] = hh;
      hh = fmaf(s_aprod[kk][tid], hh, s_hend[kk][tid]);
    }
  }
  __syncthreads();

  h = s_hstart[k][s];
  float* yp = y + ((size_t)(b * L_) + k * 64) * DI + c;
  const float* rp = xz + ((size_t)(b * L_) + k * 64) * 512 + 256 + c;
  for (int j = 0; j < 64; j += 4) {
    float4 d4 = *(const float4*)(dp + j);
    float4 x4 = *(const float4*)(xp + j);
    float dj[4] = {d4.x, d4.y, d4.z, d4.w};
    float xj[4] = {x4.x, x4.y, x4.z, x4.w};
#pragma unroll
    for (int u = 0; u < 4; ++u) {
      float Bv = bp[(size_t)(j + u) * 40];
      float Cv = cp[(size_t)(j + u) * 40];
      float dA = __expf(dj[u] * A);
      h = fmaf(dA, h, dj[u] * Bv * xj[u]);
      float p = h * Cv;
      p += __shfl_xor(p, 8, 16);
      p += __shfl_xor(p, 4, 16);
      p += __shfl_xor(p, 2, 16);
      p += __shfl_xor(p, 1, 16);
      if (s == 0) {
        float res = rp[(size_t)(j + u) * 512];
        yp[(size_t)(j + u) * DI] = (p + xj[u] * dpc) * silu_f(res);
      }
    }
  }
}

// ---------------- final fused: ob = y@W_out; +h0; rmsnorm; head; softmax; argmax (round-5) ----
__global__ __launch_bounds__(256) void final_gemm_kernel(const float* __restrict__ y,
                                                         const float* __restrict__ W_out,
                                                         const float* __restrict__ h0,
                                                         const float* __restrict__ normf_w,
                                                         const float* __restrict__ W_head,
                                                         const float* __restrict__ b_head,
                                                         float* __restrict__ pi_out,
                                                         float* __restrict__ pred_out) {
  constexpr int BM = 32, BK = 32;
  __shared__ float As[BK][BM + 4];
  __shared__ float Bs[BK][128 + 4];
  __shared__ float Wh[128 * 6];
  int tid = threadIdx.x;
  int tm = tid >> 4, tn = tid & 15;
  int bm = blockIdx.x * BM;
  for (int i = tid; i < 768; i += 256) Wh[i] = W_head[i];
  float acc[2][8] = {};
  for (int k0 = 0; k0 < DI; k0 += BK) {
    {
      int r = tid >> 3, kq = (tid & 7) * 4;
      float4 a4 = *(const float4*)&y[(size_t)(bm + r) * DI + k0 + kq];
      As[kq + 0][r] = a4.x;
      As[kq + 1][r] = a4.y;
      As[kq + 2][r] = a4.z;
      As[kq + 3][r] = a4.w;
    }
#pragma unroll
    for (int p = 0; p < 4; ++p) {
      int i = tid + p * 256;
      int r = i >> 5, c = (i & 31) * 4;
      *(float4*)&Bs[r][c] = *(const float4*)&W_out[(size_t)(k0 + r) * DM + c];
    }
    __syncthreads();
#pragma unroll
    for (int kk = 0; kk < BK; ++kk) {
      float a0 = As[kk][tm * 2], a1 = As[kk][tm * 2 + 1];
      float4 b0 = *(const float4*)&Bs[kk][tn * 4];
      float4 b1 = *(const float4*)&Bs[kk][64 + tn * 4];
      float b[8] = {b0.x, b0.y, b0.z, b0.w, b1.x, b1.y, b1.z, b1.w};
#pragma unroll
      for (int j = 0; j < 8; ++j) acc[0][j] = fmaf(a0, b[j], acc[0][j]);
#pragma unroll
      for (int j = 0; j < 8; ++j) acc[1][j] = fmaf(a1, b[j], acc[1][j]);
    }
    __syncthreads();
  }
  float4 nwa = *(const float4*)&normf_w[tn * 4];
  float4 nwb = *(const float4*)&normf_w[64 + tn * 4];
  float nw[8] = {nwa.x, nwa.y, nwa.z, nwa.w, nwb.x, nwb.y, nwb.z, nwb.w};
  float bh[6];
#pragma unroll
  for (int j = 0; j < 6; ++j) bh[j] = b_head[j];
#pragma unroll
  for (int i = 0; i < 2; ++i) {
    int row = bm + tm * 2 + i;
    float4 h0a = *(const float4*)&h0[(size_t)row * DM + tn * 4];
    float4 h0b = *(const float4*)&h0[(size_t)row * DM + 64 + tn * 4];
    float hv[8] = {acc[i][0] + h0a.x, acc[i][1] + h0a.y, acc[i][2] + h0a.z, acc[i][3] + h0a.w,
                   acc[i][4] + h0b.x, acc[i][5] + h0b.y, acc[i][6] + h0b.z, acc[i][7] + h0b.w};
    float ss = 0.f;
#pragma unroll
    for (int j = 0; j < 8; ++j) ss += hv[j] * hv[j];
    ss += __shfl_xor(ss, 1);
    ss += __shfl_xor(ss, 2);
    ss += __shfl_xor(ss, 4);
    ss += __shfl_xor(ss, 8);
    float rs = 1.f / sqrtf(ss * (1.f / 128.f) + 1e-5f);
    float lg[6] = {};
#pragma unroll
    for (int j = 0; j < 8; ++j) {
      float fm = hv[j] * rs * nw[j];
      int col = (j < 4) ? (tn * 4 + j) : (64 + tn * 4 + (j - 4));
#pragma unroll
      for (int l = 0; l < 6; ++l) lg[l] = fmaf(fm, Wh[col * 6 + l], lg[l]);
    }
#pragma unroll
    for (int l = 0; l < 6; ++l) {
      lg[l] += __shfl_xor(lg[l], 1);
      lg[l] += __shfl_xor(lg[l], 2);
      lg[l] += __shfl_xor(lg[l], 4);
      lg[l] += __shfl_xor(lg[l], 8);
      lg[l] += bh[l];
    }
    if (tn == 0) {
      float mv = lg[0];
      int am = 0;
#pragma unroll
      for (int l = 1; l < 6; ++l)
        if (lg[l] > mv) { mv = lg[l]; am = l; }
      float e[6], sum = 0.f;
#pragma unroll
      for (int l = 0; l < 6; ++l) { e[l] = __expf(lg[l] - mv); sum += e[l]; }
      float inv = 1.f / sum;
#pragma unroll
      for (int l = 0; l < 6; ++l) pi_out[(size_t)row * NL + l] = e[l] * inv;
      pred_out[row] = (float)am;
    }
  }
}

extern "C" void kernel_launch(void* const* d_in, const int* in_sizes, int n_in,
                              void* d_out, int out_size, void* d_ws, size_t ws_size,
                              hipStream_t stream) {
  const float* x = (const float*)d_in[0];
  const float* W_emb = (const float*)d_in[1];
  const float* b_emb = (const float*)d_in[2];
  const float* norm_w = (const float*)d_in[3];
  const float* W_in = (const float*)d_in[4];
  const float* conv_w = (const float*)d_in[5];
  const float* conv_b = (const float*)d_in[6];
  const float* W_x = (const float*)d_in[7];
  const float* W_dt = (const float*)d_in[8];
  const float* b_dt = (const float*)d_in[9];
  const float* A_log = (const float*)d_in[10];
  const float* Dp = (const float*)d_in[11];
  const float* W_out = (const float*)d_in[12];
  const float* normf_w = (const float*)d_in[13];
  const float* W_head = (const float*)d_in[14];
  const float* b_head = (const float*)d_in[15];

  float* ws = (float*)d_ws;
  float* h0 = ws;                      // 8192*128
  float* u = h0 + 1048576;             // 8192*128
  float* xz = u + 1048576;             // 8192*512
  float* xs_row = xz + 4194304;        // 8192*256
  float* xs_T = xs_row + 2097152;      // 1024*2048
  float* dbl = xs_T + 2097152;         // 8192*40
  float* delta_T = dbl + 327680;       // 1024*2048
  float* y = delta_T + 2097152;        // 8192*256

  // split-K partials (8*8192*128 floats) alias xz+xs_row+xs_T — dead until xz written.
  float* part = xz;
  // bf16 hi/lo split of W_emb (2 x 786KB) aliases delta_T — dead until step 6,
  // consumed only in steps 0-1.
  unsigned short* wt_hi = (unsigned short*)delta_T;
  unsigned short* wt_lo = wt_hi + (size_t)IN_DIM * DM;

  float* pi_out = (float*)d_out;
  float* pred_out = pi_out + (size_t)ROWS * NL;

  // 0) split W_emb into transposed bf16 hi/lo
  wsplit_kernel<<<192, 256, 0, stream>>>(W_emb, wt_hi, wt_lo);
  // 1) split-K emb GEMM via MFMA -> partials
  gemm_emb_mfma<<<dim3(SPLITK, ROWS / 64), 256, 0, stream>>>(x, wt_hi, wt_lo, part);
  // 2) reduce partials + bias -> h0; fused rmsnorm -> u
  reduce_rms_kernel<<<ROWS / 4, 256, 0, stream>>>(part, b_emb, norm_w, h0, u);
  // 3) xz = u @ W_in
  gemm_in<<<dim3(4, 128), 256, 0, stream>>>(u, W_in, xz);
  // 4) xs = silu(causal_dwconv(xz[:, :256]))
  conv_silu_kernel<<<dim3(4, 32, 4), 256, 0, stream>>>(xz, conv_w, conv_b, xs_row, xs_T);
  // 5) dbl = xs @ W_x
  dbl_kernel<<<256, 256, 0, stream>>>(xs_row, W_x, dbl);
  // 6) delta = softplus(dt @ W_dt + b_dt)  (transposed store)
  delta_kernel<<<256, 256, 0, stream>>>(dbl, W_dt, b_dt, delta_T);
  // 7) chunked parallel selective scan + fused ypost
  scan_kernel<<<1024, 512, 0, stream>>>(delta_T, xs_T, dbl, A_log, Dp, xz, y);
  // 8) final fused GEMM + residual + rmsnorm + head + softmax + argmax
  final_gemm_kernel<<<256, 256, 0, stream>>>(y, W_out, h0, normf_w, W_head, b_head, pi_out, pred_out);
}

// Round 10
// 357.881 us; speedup vs baseline: 1.3788x; 1.0547x over previous
//
#include <hip/hip_runtime.h>
#include <hip/hip_bf16.h>
#include <math.h>

constexpr int B_ = 4, L_ = 2048, IN_DIM = 3072, DM = 128, DI = 256, DS = 16, NL = 6;
constexpr int ROWS = B_ * L_; // 8192
constexpr int SPLITK = 8, KC = IN_DIM / SPLITK; // 384

typedef __attribute__((ext_vector_type(8))) short short8b;  // 8 bf16 (4 VGPRs)
typedef __attribute__((ext_vector_type(4))) float f32x4;

static __device__ __forceinline__ float silu_f(float x) {
  return x / (1.f + __expf(-x));
}

static __device__ __forceinline__ unsigned short f2bf_rne(float v) {
  unsigned u = __float_as_uint(v);
  unsigned r = u + 0x7FFFu + ((u >> 16) & 1u);
  return (unsigned short)(r >> 16);
}

// ---------------- prep: W_emb (3072x128 f32) -> transposed bf16 hi/lo [c][k] ----------------
__global__ __launch_bounds__(256) void wsplit_kernel(const float* __restrict__ W,
                                                     unsigned short* __restrict__ wt_hi,
                                                     unsigned short* __restrict__ wt_lo) {
  int tid = threadIdx.x;
  int c = tid & 127;
  int kc = blockIdx.x * 16 + (tid >> 7) * 8;
  short8b vh, vl;
#pragma unroll
  for (int j = 0; j < 8; ++j) {
    float v = W[(size_t)(kc + j) * DM + c];
    unsigned short h = f2bf_rne(v);
    float hf = __uint_as_float((unsigned)h << 16);
    vh[j] = (short)h;
    vl[j] = (short)f2bf_rne(v - hf);
  }
  *(short8b*)&wt_hi[(size_t)c * IN_DIM + kc] = vh;
  *(short8b*)&wt_lo[(size_t)c * IN_DIM + kc] = vl;
}

// ---------------- split-K embedding GEMM via bf16 hi/lo MFMA (round-8 verified) ----------------
__global__ __launch_bounds__(256) void gemm_emb_mfma(const float* __restrict__ A,
                                                     const unsigned short* __restrict__ wt_hi,
                                                     const unsigned short* __restrict__ wt_lo,
                                                     float* __restrict__ part) {
  constexpr int BM = 64, BK = 32, LDA = 40;  // +8 bf16 pad
  __shared__ unsigned short Ah[BM][LDA], Al[BM][LDA];
  __shared__ unsigned short Bh[DM][LDA], Bl[DM][LDA];
  int split = blockIdx.x;
  int bm = blockIdx.y * BM;
  int kb = split * KC;
  int tid = threadIdx.x;
  int w = tid >> 6, l = tid & 63;
  int fr = l & 15, fk = (l >> 4) * 8;

  f32x4 acc[8] = {};

  for (int k0 = 0; k0 < KC; k0 += BK) {
    {
      int r = tid >> 2, kq = (tid & 3) * 8;
      const float* src = &A[(size_t)(bm + r) * IN_DIM + kb + k0 + kq];
      float4 v0 = *(const float4*)src;
      float4 v1 = *(const float4*)(src + 4);
      float vv[8] = {v0.x, v0.y, v0.z, v0.w, v1.x, v1.y, v1.z, v1.w};
      short8b vh, vl;
#pragma unroll
      for (int j = 0; j < 8; ++j) {
        unsigned short h = f2bf_rne(vv[j]);
        float hf = __uint_as_float((unsigned)h << 16);
        vh[j] = (short)h;
        vl[j] = (short)f2bf_rne(vv[j] - hf);
      }
      *(short8b*)&Ah[r][kq] = vh;
      *(short8b*)&Al[r][kq] = vl;
    }
    {
      int c = tid >> 1, kq = (tid & 1) * 16;
      const unsigned short* sh = &wt_hi[(size_t)c * IN_DIM + kb + k0 + kq];
      const unsigned short* sl = &wt_lo[(size_t)c * IN_DIM + kb + k0 + kq];
      *(short8b*)&Bh[c][kq] = *(const short8b*)sh;
      *(short8b*)&Bh[c][kq + 8] = *(const short8b*)(sh + 8);
      *(short8b*)&Bl[c][kq] = *(const short8b*)sl;
      *(short8b*)&Bl[c][kq + 8] = *(const short8b*)(sl + 8);
    }
    __syncthreads();
    short8b ah = *(short8b*)&Ah[16 * w + fr][fk];
    short8b al = *(short8b*)&Al[16 * w + fr][fk];
#pragma unroll
    for (int t = 0; t < 8; ++t) {
      short8b bh = *(short8b*)&Bh[16 * t + fr][fk];
      short8b bl = *(short8b*)&Bl[16 * t + fr][fk];
      acc[t] = __builtin_amdgcn_mfma_f32_16x16x32_bf16(ah, bh, acc[t], 0, 0, 0);
      acc[t] = __builtin_amdgcn_mfma_f32_16x16x32_bf16(ah, bl, acc[t], 0, 0, 0);
      acc[t] = __builtin_amdgcn_mfma_f32_16x16x32_bf16(al, bh, acc[t], 0, 0, 0);
    }
    __syncthreads();
  }
  int orow = bm + 16 * w + (l >> 4) * 4;
#pragma unroll
  for (int t = 0; t < 8; ++t) {
#pragma unroll
    for (int r = 0; r < 4; ++r) {
      part[((size_t)split * ROWS + orow + r) * DM + 16 * t + fr] = acc[t][r];
    }
  }
}

// ---------------- reduce split-K partials + bias -> h0 ; fused rmsnorm -> u ----------------
__global__ __launch_bounds__(256) void reduce_rms_kernel(const float* __restrict__ part,
                                                         const float* __restrict__ b_emb,
                                                         const float* __restrict__ norm_w,
                                                         float* __restrict__ h0,
                                                         float* __restrict__ u) {
  int wave = threadIdx.x >> 6, lane = threadIdx.x & 63;
  int row = blockIdx.x * 4 + wave;
  float sx = 0.f, sy = 0.f;
#pragma unroll
  for (int sp = 0; sp < SPLITK; ++sp) {
    float2 v = *(const float2*)(part + ((size_t)sp * ROWS + row) * DM + 2 * lane);
    sx += v.x;
    sy += v.y;
  }
  float2 be = *(const float2*)(b_emb + 2 * lane);
  sx += be.x;
  sy += be.y;
  float2 hv = {sx, sy};
  *(float2*)(h0 + (size_t)row * DM + 2 * lane) = hv;
  float ss = sx * sx + sy * sy;
#pragma unroll
  for (int o = 32; o >= 1; o >>= 1) ss += __shfl_xor(ss, o);
  float rs = 1.f / sqrtf(ss * (1.f / 128.f) + 1e-5f);
  float2 wv = *(const float2*)(norm_w + 2 * lane);
  float2 o2 = {sx * rs * wv.x, sy * rs * wv.y};
  *(float2*)(u + (size_t)row * DM + 2 * lane) = o2;
}

// ---------------- xz = u @ W_in : M=8192, K=128, N=512 (round-5 verified) ----------------
__global__ __launch_bounds__(256) void gemm_in(const float* __restrict__ A,
                                               const float* __restrict__ Bv,
                                               float* __restrict__ C) {
  constexpr int BM = 64, BK = 32, N = 512;
  __shared__ float As[BK][BM + 4];
  __shared__ float Bs[BK][128 + 4];
  int bn = blockIdx.x * 128;
  int bm = blockIdx.y * BM;
  int tid = threadIdx.x;
  int tm = tid >> 4, tn = tid & 15;
  float acc[4][8] = {};
  for (int k0 = 0; k0 < DM; k0 += BK) {
#pragma unroll
    for (int p = 0; p < 2; ++p) {
      int i = tid + p * 256;
      int r = i >> 3, kq = (i & 7) * 4;
      float4 a4 = *(const float4*)&A[(size_t)(bm + r) * DM + k0 + kq];
      As[kq + 0][r] = a4.x;
      As[kq + 1][r] = a4.y;
      As[kq + 2][r] = a4.z;
      As[kq + 3][r] = a4.w;
    }
#pragma unroll
    for (int p = 0; p < 4; ++p) {
      int i = tid + p * 256;
      int r = i >> 5, c = (i & 31) * 4;
      *(float4*)&Bs[r][c] = *(const float4*)&Bv[(size_t)(k0 + r) * N + bn + c];
    }
    __syncthreads();
#pragma unroll
    for (int kk = 0; kk < BK; ++kk) {
      float4 a4 = *(const float4*)&As[kk][tm * 4];
      float4 b0 = *(const float4*)&Bs[kk][tn * 4];
      float4 b1 = *(const float4*)&Bs[kk][64 + tn * 4];
      float a[4] = {a4.x, a4.y, a4.z, a4.w};
      float b[8] = {b0.x, b0.y, b0.z, b0.w, b1.x, b1.y, b1.z, b1.w};
#pragma unroll
      for (int i = 0; i < 4; ++i)
#pragma unroll
        for (int j = 0; j < 8; ++j) acc[i][j] = fmaf(a[i], b[j], acc[i][j]);
    }
    __syncthreads();
  }
#pragma unroll
  for (int i = 0; i < 4; ++i) {
    size_t rowoff = (size_t)(bm + tm * 4 + i) * N + bn;
    float4 o0 = {acc[i][0], acc[i][1], acc[i][2], acc[i][3]};
    float4 o1 = {acc[i][4], acc[i][5], acc[i][6], acc[i][7]};
    *(float4*)&C[rowoff + tn * 4] = o0;
    *(float4*)&C[rowoff + 64 + tn * 4] = o1;
  }
}

// ---------------- conv + silu (tiles 0-3) / res transpose (tiles 4-7) ----------------
// tiles 0-3: xs = silu(causal_dwconv(xz[:, :256])) -> xs_row + xs_T
// tiles 4-7: res_T[b*DI+c][l] = xz[b*L+l][256+c]  (raw; scan applies silu)
__global__ __launch_bounds__(256) void conv_silu_kernel(const float* __restrict__ xz,
                                                        const float* __restrict__ conv_w,
                                                        const float* __restrict__ conv_b,
                                                        float* __restrict__ xs_row,
                                                        float* __restrict__ xs_T,
                                                        float* __restrict__ res_T) {
  __shared__ float tile[64][65];
  __shared__ float cw[64][4];
  __shared__ float cb[64];
  int cx = blockIdx.x;
  int b = blockIdx.z, l0 = blockIdx.y * 64;
  int tid = threadIdx.x;
  int cl = tid % 64;
  int lbase = tid / 64;  // 0..3
  if (cx < 4) {
    int c0 = cx * 64;
    cw[tid / 4][tid % 4] = conv_w[(size_t)c0 * 4 + tid];
    if (tid < 64) cb[tid] = conv_b[c0 + tid];
    __syncthreads();
#pragma unroll
    for (int i = 0; i < 16; ++i) {
      int ll = lbase + 4 * i;
      int l = l0 + ll;
      float acc = cb[cl];
#pragma unroll
      for (int k = 0; k < 4; ++k) {
        int li = l + k - 3;
        if (li >= 0) acc = fmaf(xz[((size_t)(b * L_ + li)) * 512 + c0 + cl], cw[cl][k], acc);
      }
      tile[ll][cl] = silu_f(acc);
    }
    __syncthreads();
    for (int i = tid; i < 4096; i += 256) {
      int lr = i / 64, c = i % 64;
      xs_row[((size_t)(b * L_ + l0 + lr)) * DI + c0 + c] = tile[lr][c];
    }
    for (int i = tid; i < 4096; i += 256) {
      int c = i / 64, lr = i % 64;
      xs_T[((size_t)(b * DI + c0 + c)) * L_ + l0 + lr] = tile[lr][c];
    }
  } else {
    int c0 = (cx - 4) * 64;
#pragma unroll
    for (int i = 0; i < 16; ++i) {
      int ll = lbase + 4 * i;
      tile[ll][cl] = xz[((size_t)(b * L_ + l0 + ll)) * 512 + 256 + c0 + cl];
    }
    __syncthreads();
    for (int i = tid; i < 4096; i += 256) {
      int c = i / 64, lr = i % 64;
      res_T[((size_t)(b * DI + c0 + c)) * L_ + l0 + lr] = tile[lr][c];
    }
  }
}

// ---------------- dbl = xs @ W_x (256 -> 40), 32 rows/block, grid 256 (round-5) ----------------
__global__ __launch_bounds__(256) void dbl_kernel(const float* __restrict__ xs_row,
                                                  const float* __restrict__ W_x,
                                                  float* __restrict__ dbl) {
  __shared__ float Xs[32][257];
  __shared__ float Wx[256 * 40];
  int tid = threadIdx.x;
  int r0 = blockIdx.x * 32;
  for (int i = tid; i < 32 * 64; i += 256) {
    int r = i >> 6, kq = (i & 63) * 4;
    float4 v = *(const float4*)&xs_row[(size_t)(r0 + r) * DI + kq];
    Xs[r][kq + 0] = v.x;
    Xs[r][kq + 1] = v.y;
    Xs[r][kq + 2] = v.z;
    Xs[r][kq + 3] = v.w;
  }
  for (int i = tid; i < 256 * 40; i += 256) Wx[i] = W_x[i];
  __syncthreads();
  int r = tid & 31, q = tid >> 5;  // q in 0..7 -> output cols q*5..q*5+4
  float acc[5] = {};
  for (int k = 0; k < 256; ++k) {
    float v = Xs[r][k];
#pragma unroll
    for (int j = 0; j < 5; ++j) acc[j] = fmaf(v, Wx[k * 40 + q * 5 + j], acc[j]);
  }
#pragma unroll
  for (int j = 0; j < 5; ++j) dbl[(size_t)(r0 + r) * 40 + q * 5 + j] = acc[j];
}

// ---------------- delta = softplus(dt @ W_dt + b_dt), transposed, 32 rows/block (round-5) ----
__global__ __launch_bounds__(256) void delta_kernel(const float* __restrict__ dbl,
                                                    const float* __restrict__ W_dt,
                                                    const float* __restrict__ b_dt,
                                                    float* __restrict__ delta_T) {
  __shared__ float Tile[32][257];
  __shared__ float Dt[32][8];
  __shared__ float Wdt[8 * 256];
  int tid = threadIdx.x;
  int r0 = blockIdx.x * 32;
  int b = r0 / L_, l0 = r0 % L_;
  if (tid < 256) {
    int r = tid >> 3, k = tid & 7;
    Dt[r][k] = dbl[(size_t)(r0 + r) * 40 + k];
  }
  for (int i = tid; i < 8 * 256; i += 256) Wdt[i] = W_dt[i];
  __syncthreads();
  int c = tid;
  float bd = b_dt[c];
  for (int r = 0; r < 32; ++r) {
    float a = bd;
#pragma unroll
    for (int k = 0; k < 8; ++k) a = fmaf(Dt[r][k], Wdt[k * 256 + c], a);
    Tile[r][c] = (a > 20.f) ? a : log1pf(__expf(a));
  }
  __syncthreads();
  for (int i = tid; i < 32 * 256; i += 256) {
    int cc = i >> 5, rr = i & 31;
    delta_T[((size_t)(b * DI + cc)) * L_ + l0 + rr] = Tile[rr][cc];
  }
}

// ---------------- chunked parallel selective scan + fused ypost ----------------
// resy: on entry holds res_T[g][l] (raw res); overwritten in place with
// y_T[g][l] = (sum_s h*C + xs*Dp) * silu(res). Safe: each address is read
// then written by exactly one thread (in-thread dependency orders them).
__global__ __launch_bounds__(512) void scan_kernel(const float* __restrict__ delta_T,
                                                   const float* __restrict__ xs_T,
                                                   const float* __restrict__ dbl,
                                                   const float* __restrict__ A_log,
                                                   const float* __restrict__ Dp,
                                                   float* resy) {
  __shared__ float s_aprod[32][16];
  __shared__ float s_hend[32][16];
  __shared__ float s_hstart[32][16];
  int tid = threadIdx.x;
  int k = tid >> 4, s = tid & 15;   // chunk, state
  int g = blockIdx.x;               // b*256 + c
  int b = g >> 8, c = g & 255;
  float A = -__expf(A_log[c * DS + s]);
  float dpc = Dp[c];
  const float* dp = delta_T + (size_t)g * L_ + k * 64;
  const float* xp = xs_T + (size_t)g * L_ + k * 64;
  const float* bp = dbl + ((size_t)(b * L_ + k * 64)) * 40 + 8 + s;
  const float* cp = dbl + ((size_t)(b * L_ + k * 64)) * 40 + 24 + s;

  float aprod = 1.f, h = 0.f;
  for (int j = 0; j < 64; j += 4) {
    float4 d4 = *(const float4*)(dp + j);
    float4 x4 = *(const float4*)(xp + j);
    float dj[4] = {d4.x, d4.y, d4.z, d4.w};
    float xj[4] = {x4.x, x4.y, x4.z, x4.w};
#pragma unroll
    for (int u = 0; u < 4; ++u) {
      float Bv = bp[(size_t)(j + u) * 40];
      float dA = __expf(dj[u] * A);
      aprod *= dA;
      h = fmaf(dA, h, dj[u] * Bv * xj[u]);
    }
  }
  s_aprod[k][s] = aprod;
  s_hend[k][s] = h;
  __syncthreads();

  if (tid < 16) {
    float hh = 0.f;
    for (int kk = 0; kk < 32; ++kk) {
      s_hstart[kk][tid] = hh;
      hh = fmaf(s_aprod[kk][tid], hh, s_hend[kk][tid]);
    }
  }
  __syncthreads();

  h = s_hstart[k][s];
  float* rp = resy + (size_t)g * L_ + k * 64;
  for (int j = 0; j < 64; j += 4) {
    float4 d4 = *(const float4*)(dp + j);
    float4 x4 = *(const float4*)(xp + j);
    float4 r4 = *(const float4*)(rp + j);
    float dj[4] = {d4.x, d4.y, d4.z, d4.w};
    float xj[4] = {x4.x, x4.y, x4.z, x4.w};
    float rj[4] = {r4.x, r4.y, r4.z, r4.w};
    float p4[4];
#pragma unroll
    for (int u = 0; u < 4; ++u) {
      float Bv = bp[(size_t)(j + u) * 40];
      float Cv = cp[(size_t)(j + u) * 40];
      float dA = __expf(dj[u] * A);
      h = fmaf(dA, h, dj[u] * Bv * xj[u]);
      float p = h * Cv;
      p += __shfl_xor(p, 8, 16);
      p += __shfl_xor(p, 4, 16);
      p += __shfl_xor(p, 2, 16);
      p += __shfl_xor(p, 1, 16);
      p4[u] = (p + xj[u] * dpc) * silu_f(rj[u]);
    }
    if (s == 0) {
      float4 o = {p4[0], p4[1], p4[2], p4[3]};
      *(float4*)(rp + j) = o;
    }
  }
}

// ---------------- final fused: ob = y@W_out; +h0; rmsnorm; head; softmax; argmax ----------------
// A-tile loaded from y_T (coalesced: 32 channel-rows x 32 contiguous l floats).
__global__ __launch_bounds__(256) void final_gemm_kernel(const float* __restrict__ yT,
                                                         const float* __restrict__ W_out,
                                                         const float* __restrict__ h0,
                                                         const float* __restrict__ normf_w,
                                                         const float* __restrict__ W_head,
                                                         const float* __restrict__ b_head,
                                                         float* __restrict__ pi_out,
                                                         float* __restrict__ pred_out) {
  constexpr int BM = 32, BK = 32;
  __shared__ float As[BK][BM + 4];
  __shared__ float Bs[BK][128 + 4];
  __shared__ float Wh[128 * 6];
  int tid = threadIdx.x;
  int tm = tid >> 4, tn = tid & 15;
  int bm = blockIdx.x * BM;
  int b = bm >> 11, l0 = bm & (L_ - 1);
  for (int i = tid; i < 768; i += 256) Wh[i] = W_head[i];
  float acc[2][8] = {};
  for (int k0 = 0; k0 < DI; k0 += BK) {
    {
      int cc = tid >> 3, lq = (tid & 7) * 4;
      float4 v = *(const float4*)&yT[((size_t)(b * DI + k0 + cc)) * L_ + l0 + lq];
      *(float4*)&As[cc][lq] = v;
    }
#pragma unroll
    for (int p = 0; p < 4; ++p) {
      int i = tid + p * 256;
      int r = i >> 5, c = (i & 31) * 4;
      *(float4*)&Bs[r][c] = *(const float4*)&W_out[(size_t)(k0 + r) * DM + c];
    }
    __syncthreads();
#pragma unroll
    for (int kk = 0; kk < BK; ++kk) {
      float a0 = As[kk][tm * 2], a1 = As[kk][tm * 2 + 1];
      float4 b0 = *(const float4*)&Bs[kk][tn * 4];
      float4 b1 = *(const float4*)&Bs[kk][64 + tn * 4];
      float bb[8] = {b0.x, b0.y, b0.z, b0.w, b1.x, b1.y, b1.z, b1.w};
#pragma unroll
      for (int j = 0; j < 8; ++j) acc[0][j] = fmaf(a0, bb[j], acc[0][j]);
#pragma unroll
      for (int j = 0; j < 8; ++j) acc[1][j] = fmaf(a1, bb[j], acc[1][j]);
    }
    __syncthreads();
  }
  float4 nwa = *(const float4*)&normf_w[tn * 4];
  float4 nwb = *(const float4*)&normf_w[64 + tn * 4];
  float nw[8] = {nwa.x, nwa.y, nwa.z, nwa.w, nwb.x, nwb.y, nwb.z, nwb.w};
  float bh[6];
#pragma unroll
  for (int j = 0; j < 6; ++j) bh[j] = b_head[j];
#pragma unroll
  for (int i = 0; i < 2; ++i) {
    int row = bm + tm * 2 + i;
    float4 h0a = *(const float4*)&h0[(size_t)row * DM + tn * 4];
    float4 h0b = *(const float4*)&h0[(size_t)row * DM + 64 + tn * 4];
    float hv[8] = {acc[i][0] + h0a.x, acc[i][1] + h0a.y, acc[i][2] + h0a.z, acc[i][3] + h0a.w,
                   acc[i][4] + h0b.x, acc[i][5] + h0b.y, acc[i][6] + h0b.z, acc[i][7] + h0b.w};
    float ss = 0.f;
#pragma unroll
    for (int j = 0; j < 8; ++j) ss += hv[j] * hv[j];
    ss += __shfl_xor(ss, 1);
    ss += __shfl_xor(ss, 2);
    ss += __shfl_xor(ss, 4);
    ss += __shfl_xor(ss, 8);
    float rs = 1.f / sqrtf(ss * (1.f / 128.f) + 1e-5f);
    float lg[6] = {};
#pragma unroll
    for (int j = 0; j < 8; ++j) {
      float fm = hv[j] * rs * nw[j];
      int col = (j < 4) ? (tn * 4 + j) : (64 + tn * 4 + (j - 4));
#pragma unroll
      for (int l = 0; l < 6; ++l) lg[l] = fmaf(fm, Wh[col * 6 + l], lg[l]);
    }
#pragma unroll
    for (int l = 0; l < 6; ++l) {
      lg[l] += __shfl_xor(lg[l], 1);
      lg[l] += __shfl_xor(lg[l], 2);
      lg[l] += __shfl_xor(lg[l], 4);
      lg[l] += __shfl_xor(lg[l], 8);
      lg[l] += bh[l];
    }
    if (tn == 0) {
      float mv = lg[0];
      int am = 0;
#pragma unroll
      for (int l = 1; l < 6; ++l)
        if (lg[l] > mv) { mv = lg[l]; am = l; }
      float e[6], sum = 0.f;
#pragma unroll
      for (int l = 0; l < 6; ++l) { e[l] = __expf(lg[l] - mv); sum += e[l]; }
      float inv = 1.f / sum;
#pragma unroll
      for (int l = 0; l < 6; ++l) pi_out[(size_t)row * NL + l] = e[l] * inv;
      pred_out[row] = (float)am;
    }
  }
}

extern "C" void kernel_launch(void* const* d_in, const int* in_sizes, int n_in,
                              void* d_out, int out_size, void* d_ws, size_t ws_size,
                              hipStream_t stream) {
  const float* x = (const float*)d_in[0];
  const float* W_emb = (const float*)d_in[1];
  const float* b_emb = (const float*)d_in[2];
  const float* norm_w = (const float*)d_in[3];
  const float* W_in = (const float*)d_in[4];
  const float* conv_w = (const float*)d_in[5];
  const float* conv_b = (const float*)d_in[6];
  const float* W_x = (const float*)d_in[7];
  const float* W_dt = (const float*)d_in[8];
  const float* b_dt = (const float*)d_in[9];
  const float* A_log = (const float*)d_in[10];
  const float* Dp = (const float*)d_in[11];
  const float* W_out = (const float*)d_in[12];
  const float* normf_w = (const float*)d_in[13];
  const float* W_head = (const float*)d_in[14];
  const float* b_head = (const float*)d_in[15];

  float* ws = (float*)d_ws;
  float* h0 = ws;                      // 8192*128
  float* u = h0 + 1048576;             // 8192*128
  float* xz = u + 1048576;             // 8192*512
  float* xs_row = xz + 4194304;        // 8192*256
  float* xs_T = xs_row + 2097152;      // 1024*2048
  float* dbl = xs_T + 2097152;         // 8192*40
  float* delta_T = dbl + 327680;       // 1024*2048
  float* resy = delta_T + 2097152;     // 1024*2048: res_T then y_T (in place)

  // split-K partials (8*8192*128 floats) alias xz+xs_row+xs_T — dead until xz written.
  float* part = xz;
  // bf16 hi/lo split of W_emb (2 x 786KB) aliases delta_T — dead until step 6.
  unsigned short* wt_hi = (unsigned short*)delta_T;
  unsigned short* wt_lo = wt_hi + (size_t)IN_DIM * DM;

  float* pi_out = (float*)d_out;
  float* pred_out = pi_out + (size_t)ROWS * NL;

  // 0) split W_emb into transposed bf16 hi/lo
  wsplit_kernel<<<192, 256, 0, stream>>>(W_emb, wt_hi, wt_lo);
  // 1) split-K emb GEMM via MFMA -> partials
  gemm_emb_mfma<<<dim3(SPLITK, ROWS / 64), 256, 0, stream>>>(x, wt_hi, wt_lo, part);
  // 2) reduce partials + bias -> h0; fused rmsnorm -> u
  reduce_rms_kernel<<<ROWS / 4, 256, 0, stream>>>(part, b_emb, norm_w, h0, u);
  // 3) xz = u @ W_in
  gemm_in<<<dim3(4, 128), 256, 0, stream>>>(u, W_in, xz);
  // 4) conv+silu (tiles 0-3) and res transpose (tiles 4-7)
  conv_silu_kernel<<<dim3(8, 32, 4), 256, 0, stream>>>(xz, conv_w, conv_b, xs_row, xs_T, resy);
  // 5) dbl = xs @ W_x
  dbl_kernel<<<256, 256, 0, stream>>>(xs_row, W_x, dbl);
  // 6) delta = softplus(dt @ W_dt + b_dt)  (transposed store)
  delta_kernel<<<256, 256, 0, stream>>>(dbl, W_dt, b_dt, delta_T);
  // 7) chunked parallel selective scan + fused ypost (res_T -> y_T in place)
  scan_kernel<<<1024, 512, 0, stream>>>(delta_T, xs_T, dbl, A_log, Dp, resy);
  // 8) final fused GEMM (A from y_T) + residual + rmsnorm + head + softmax + argmax
  final_gemm_kernel<<<256, 256, 0, stream>>>(resy, W_out, h0, normf_w, W_head, b_head, pi_out, pred_out);
}